// Round 8
// baseline (272.632 us; speedup 1.0000x reference)
//
#include <hip/hip_runtime.h>
#include <math.h>

typedef __attribute__((ext_vector_type(8))) short bf16x8;
typedef __attribute__((ext_vector_type(4))) float f32x4;

__device__ __forceinline__ unsigned short f32_to_bf16_rne(float f) {
    unsigned int u = __float_as_uint(f);
    unsigned int r = (u + 0x7FFFu + ((u >> 16) & 1u)) >> 16;
    return (unsigned short)r;
}
__device__ __forceinline__ float bf16_to_f32(unsigned short h) {
    return __uint_as_float(((unsigned int)h) << 16);
}
__device__ __forceinline__ unsigned int pck(unsigned short a, unsigned short b) {
    return (unsigned int)a | ((unsigned int)b << 16);
}

// ---------------------------------------------------------------------------
// K0: k_prep — split weights to bf16 hi/lo, pack into MFMA-frag-chunk layouts.
//  Wfc      -> Bpkh/Bpkl [24 steps][16 frags][64][8]      (classes padded 256)
//  Wl/Wm/Ws -> B2h/B2l   [24 tiles32][24 steps][2][64][8] (ff cols, 32/tile)
// granule: idx = k_oct*16 + (col&15), elem = k&7 (MFMA B lane map).
// ---------------------------------------------------------------------------
__global__ __launch_bounds__(256) void k_prep(
    const float* __restrict__ Wfc, const float* __restrict__ Wl,
    const float* __restrict__ Wm, const float* __restrict__ Ws,
    unsigned short* __restrict__ Bpkh, unsigned short* __restrict__ Bpkl,
    unsigned short* __restrict__ B2h, unsigned short* __restrict__ B2l)
{
    const int blk = blockIdx.x, tid = threadIdx.x;
    const float* src; int idx, rows, cbase; bool isfc;
    if (blk < 192)      { isfc = true;  idx = blk * 256 + tid;         src = Wfc; rows = 200; cbase = 0; }
    else if (blk < 336) { isfc = false; idx = (blk - 192) * 256 + tid; src = Wl;  rows = 192; cbase = 0; }
    else if (blk < 480) { isfc = false; idx = (blk - 336) * 256 + tid; src = Wm;  rows = 192; cbase = 192; }
    else                { isfc = false; idx = (blk - 480) * 256 + tid; src = Ws;  rows = 384; cbase = 384; }
    const int c = idx / 192;            // local row (class/col)
    const int kk = (idx % 192) * 4;     // k base (multiple of 4)
    unsigned short h[4] = {0, 0, 0, 0}, l[4] = {0, 0, 0, 0};
    if (c < rows) {
        const float4 w = *(const float4*)&src[(size_t)c * 768 + kk];
        const float wv[4] = {w.x, w.y, w.z, w.w};
#pragma unroll
        for (int j = 0; j < 4; ++j) {
            h[j] = f32_to_bf16_rne(wv[j]);
            l[j] = f32_to_bf16_rne(wv[j] - bf16_to_f32(h[j]));
        }
    }
    const int step = kk >> 5, oct = (kk & 31) >> 3, elem = kk & 7;
    const uint2 uh = make_uint2(pck(h[0], h[1]), pck(h[2], h[3]));
    const uint2 ul = make_uint2(pck(l[0], l[1]), pck(l[2], l[3]));
    if (isfc) {
        const size_t off = (size_t)((step * 16 + (c >> 4)) * 64 + oct * 16 + (c & 15)) * 8 + elem;
        *(uint2*)&Bpkh[off] = uh;
        *(uint2*)&Bpkl[off] = ul;
    } else {
        const int cg = cbase + c;
        const int tt = cg >> 5, cc = cg & 31;
        const size_t off = (size_t)(((tt * 24 + step) * 2 + (cc >> 4)) * 64 + oct * 16 + (cc & 15)) * 8 + elem;
        *(uint2*)&B2h[off] = uh;
        *(uint2*)&B2l[off] = ul;
    }
}

// ---------------------------------------------------------------------------
// K1: logits GEMM + per-block softmax PARTIALS. BM=32, BN=128, BK=32.
// grid (392, 2) = 784 blocks; 4 waves, wave = 32 rows x 32 cols (2Mx2N frags).
// Single-buffer LDS (21.5 KB), issue-early/write-late, 2 barriers/step.
// Epilogue: rowwise (max m, sum exp) over this block's 128 cols -> pmax/psum.
// ---------------------------------------------------------------------------
__global__ __launch_bounds__(256) void k_logits_p(
    const float* __restrict__ x, const unsigned short* __restrict__ Bpkh,
    const unsigned short* __restrict__ Bpkl, const float* __restrict__ bfc,
    float* __restrict__ pmax, float* __restrict__ psum)
{
    __shared__ unsigned short Ah[2][64][8], Al[2][64][8];   // 4 KB
    __shared__ unsigned short Bh[8][64][8], Bl[8][64][8];   // 16 KB
    __shared__ float sbias[128];
    __shared__ float red[4][32], red2[4][32];

    const int tid = threadIdx.x;
    const int lane = tid & 63;
    const int wid = tid >> 6;                 // n-wave 0..3
    const int row0 = blockIdx.x * 32;
    const int cb = blockIdx.y;                // col-half

    if (tid < 128) {
        const int c = cb * 128 + tid;
        sbias[tid] = (c < 200) ? bfc[c] : -1e30f;
    }

    const int ar = tid & 31, kq = tid >> 5;   // A: row, k-quad(4 floats)
    const float* xb = x + (size_t)(row0 + ar) * 768 + kq * 4;
    const uint4* bhs = (const uint4*)Bpkh;
    const uint4* bls = (const uint4*)Bpkl;

    float ag[4];
    uint4 bgh[2], bgl[2];

    f32x4 acc[2][2];
    const f32x4 z = {0.f, 0.f, 0.f, 0.f};
#pragma unroll
    for (int mf = 0; mf < 2; ++mf)
#pragma unroll
        for (int q = 0; q < 2; ++q) acc[mf][q] = z;

    auto LOADAB = [&](int t) {
        const float4 v = *(const float4*)(xb + t * 32);
        ag[0] = v.x; ag[1] = v.y; ag[2] = v.z; ag[3] = v.w;
        const int base = t * 1024 + cb * 512;
#pragma unroll
        for (int j = 0; j < 2; ++j) {
            bgh[j] = bhs[base + j * 256 + tid];
            bgl[j] = bls[base + j * 256 + tid];
        }
    };
    auto WRITEAB = [&]() {
        unsigned short h[4], l[4];
#pragma unroll
        for (int j = 0; j < 4; ++j) {
            h[j] = f32_to_bf16_rne(ag[j]);
            l[j] = f32_to_bf16_rne(ag[j] - bf16_to_f32(h[j]));
        }
        *(uint2*)&Ah[ar >> 4][(kq >> 1) * 16 + (ar & 15)][(kq & 1) * 4] =
            make_uint2(pck(h[0], h[1]), pck(h[2], h[3]));
        *(uint2*)&Al[ar >> 4][(kq >> 1) * 16 + (ar & 15)][(kq & 1) * 4] =
            make_uint2(pck(l[0], l[1]), pck(l[2], l[3]));
        uint4* bdh = (uint4*)&Bh[0][0][0];
        uint4* bdl = (uint4*)&Bl[0][0][0];
#pragma unroll
        for (int j = 0; j < 2; ++j) {
            bdh[j * 256 + tid] = bgh[j];
            bdl[j * 256 + tid] = bgl[j];
        }
    };

    LOADAB(0);
    WRITEAB();
    __syncthreads();

    for (int t = 0; t < 24; ++t) {
        if (t < 23) LOADAB(t + 1);            // overlaps MFMA below
        bf16x8 ah[2], al2[2];
#pragma unroll
        for (int mf = 0; mf < 2; ++mf) {
            ah[mf]  = *(const bf16x8*)&Ah[mf][lane][0];
            al2[mf] = *(const bf16x8*)&Al[mf][lane][0];
        }
#pragma unroll
        for (int q = 0; q < 2; ++q) {
            const bf16x8 bh = *(const bf16x8*)&Bh[wid * 2 + q][lane][0];
            const bf16x8 bl = *(const bf16x8*)&Bl[wid * 2 + q][lane][0];
#pragma unroll
            for (int mf = 0; mf < 2; ++mf) {
                acc[mf][q] = __builtin_amdgcn_mfma_f32_16x16x32_bf16(al2[mf], bh, acc[mf][q], 0, 0, 0);
                acc[mf][q] = __builtin_amdgcn_mfma_f32_16x16x32_bf16(ah[mf], bl, acc[mf][q], 0, 0, 0);
                acc[mf][q] = __builtin_amdgcn_mfma_f32_16x16x32_bf16(ah[mf], bh, acc[mf][q], 0, 0, 0);
            }
        }
        __syncthreads();                      // all waves done reading LDS[t]
        if (t < 23) {
            WRITEAB();                        // vmcnt waits loads issued above
            __syncthreads();
        }
    }

    // ---- softmax partials over this block's 128 cols ----
    // acc[mf][q][r] = logit[row=mf*16+(lane>>4)*4+r][col=wid*32+q*16+(lane&15)]
    float bv[2];
#pragma unroll
    for (int q = 0; q < 2; ++q) bv[q] = sbias[wid * 32 + q * 16 + (lane & 15)];

#pragma unroll
    for (int mf = 0; mf < 2; ++mf)
#pragma unroll
        for (int r = 0; r < 4; ++r) {
            float mx = fmaxf(acc[mf][0][r] + bv[0], acc[mf][1][r] + bv[1]);
#pragma unroll
            for (int s = 1; s < 16; s <<= 1) mx = fmaxf(mx, __shfl_xor(mx, s, 64));
            if ((lane & 15) == 0) red[wid][mf * 16 + (lane >> 4) * 4 + r] = mx;
        }
    __syncthreads();
#pragma unroll
    for (int mf = 0; mf < 2; ++mf)
#pragma unroll
        for (int r = 0; r < 4; ++r) {
            const int row = mf * 16 + (lane >> 4) * 4 + r;
            const float m = fmaxf(fmaxf(red[0][row], red[1][row]),
                                  fmaxf(red[2][row], red[3][row]));
            float se = __expf(acc[mf][0][r] + bv[0] - m) + __expf(acc[mf][1][r] + bv[1] - m);
#pragma unroll
            for (int s = 1; s < 16; s <<= 1) se += __shfl_xor(se, s, 64);
            if ((lane & 15) == 0) red2[wid][row] = se;
        }
    __syncthreads();
    if (wid == 0 && (lane & 15) == 0) {
#pragma unroll
        for (int mf = 0; mf < 2; ++mf)
#pragma unroll
            for (int r = 0; r < 4; ++r) {
                const int row = mf * 16 + (lane >> 4) * 4 + r;
                const float m = fmaxf(fmaxf(red[0][row], red[1][row]),
                                      fmaxf(red[2][row], red[3][row]));
                pmax[(size_t)(row0 + row) * 2 + cb] = m;
                psum[(size_t)(row0 + row) * 2 + cb] =
                    red2[0][row] + red2[1][row] + red2[2][row] + red2[3][row];
            }
    }
}

// ---------------------------------------------------------------------------
// K2: combine softmax partials -> maxprob; pool 8x8/stride3/pad2; mask; argmax.
// ---------------------------------------------------------------------------
__global__ void k_sel(const float* __restrict__ pmax, const float* __restrict__ psum,
                      const float* __restrict__ mask, int* __restrict__ sel)
{
    __shared__ float mp[784];
    __shared__ float pl[81];
    const int b = blockIdx.x, tid = threadIdx.x;
    for (int i = tid; i < 784; i += blockDim.x) {
        const size_t row = (size_t)b * 784 + i;
        const float m0 = pmax[row * 2], m1 = pmax[row * 2 + 1];
        const float s0 = psum[row * 2], s1 = psum[row * 2 + 1];
        const float M = fmaxf(m0, m1);
        mp[i] = 1.0f / (s0 * __expf(m0 - M) + s1 * __expf(m1 - M));
    }
    __syncthreads();
    if (tid < 81) {
        const int pr = tid / 9, pc = tid % 9;
        float s = 0.f;
        for (int ki = 0; ki < 8; ++ki) {
            const int y = pr * 3 - 2 + ki;
            if (y < 0 || y >= 28) continue;
            for (int kj = 0; kj < 8; ++kj) {
                const int xx = pc * 3 - 2 + kj;
                if (xx < 0 || xx >= 28) continue;
                s += mp[y * 28 + xx];
            }
        }
        pl[tid] = mask[b * 81 + tid] * (s * (1.f / 64.f));
    }
    __syncthreads();
    if (tid == 0) {
        float best = pl[0]; int bi = 0;
        for (int i = 1; i < 81; ++i) if (pl[i] > best) { best = pl[i]; bi = i; }
        sel[b] = bi;
    }
}

__device__ __forceinline__ void rcoef8(int o, int n, int& f0, int& f1, float& w)
{
    float s = (o + 0.5f) * ((float)n * 0.125f) - 0.5f;
    s = fminf(fmaxf(s, 0.f), (float)(n - 1));
    f0 = (int)s;
    w = s - (float)f0;
    f1 = f0 + 1; if (f1 > n - 1) f1 = n - 1;
}

// ---------------------------------------------------------------------------
// K3: fused build + ff GEMM. BM=64(window rows), BN=32, grid = 16 b x 24 tiles
// = 384 blocks. 4 waves; wave = m-frag (16 rows) x 32 cols. LDS 12 KB,
// single-buffer, issue-early/write-late. Gather->reg, shfl bilinear (verified).
// ---------------------------------------------------------------------------
__global__ __launch_bounds__(256) void k_ff(
    const float* __restrict__ x, const int* __restrict__ sel,
    const unsigned short* __restrict__ B2h, const unsigned short* __restrict__ B2l,
    const float* __restrict__ bl, const float* __restrict__ bm,
    const float* __restrict__ bs_, float* __restrict__ out)
{
    __shared__ unsigned short AhS[4][64][8], AlS[4][64][8];  // 8 KB
    __shared__ unsigned short BhS[2][64][8], BlS[2][64][8];  // 4 KB

    const int blk = blockIdx.x;
    const int b = blk / 24, t = blk % 24;
    const int n0 = t * 32;
    const int seg = (t < 6) ? 0 : ((t < 12) ? 1 : 2);
    const float* bias = (seg == 0) ? (bl + t * 32)
                      : (seg == 1) ? (bm + (t - 6) * 32)
                                   : (bs_ + (t - 12) * 32);
    const int s = sel[b];
    const int wy0 = (s / 9) * 3 - 2, wx0 = (s % 9) * 3 - 2;

    const int tid = threadIdx.x;
    const int lane = tid & 63;
    const int wid = tid >> 6;     // staging: k-octet; compute: m-frag

    // gather: lane = window position (8x8), wave = k-octet
    const int gy = wy0 + (lane >> 3), gx = wx0 + (lane & 7);
    const bool inb = (gy >= 0 && gy < 28 && gx >= 0 && gx < 28);
    const float* xsrc = x + ((size_t)b * 784 + (inb ? (gy * 28 + gx) : 0)) * 768 + wid * 8;

    // bilinear corners for output row = lane
    int r00, r01, r10, r11; float fx = 0.f, fy = 0.f;
    if (seg == 0) { r00 = r01 = r10 = r11 = lane; }
    else {
        const int nn = (seg == 1) ? 6 : 4, off = (seg == 1) ? 1 : 2;
        int f0y, f1y, f0x, f1x;
        rcoef8(lane >> 3, nn, f0y, f1y, fy);
        rcoef8(lane & 7, nn, f0x, f1x, fx);
        r00 = (off + f0y) * 8 + off + f0x;
        r01 = (off + f0y) * 8 + off + f1x;
        r10 = (off + f1y) * 8 + off + f0x;
        r11 = (off + f1y) * 8 + off + f1x;
    }

    // B: packed per (tile, step): 128 uint4 per half
    const uint4* b2h = (const uint4*)B2h + (size_t)t * 24 * 128;
    const uint4* b2l = (const uint4*)B2l + (size_t)t * 24 * 128;

    float g[8];
    uint4 b_r;

    f32x4 acc[2];
    const f32x4 z = {0.f, 0.f, 0.f, 0.f};
    acc[0] = z; acc[1] = z;

    auto LOAD = [&](int st) {
        if (inb) {
            const float4 v0 = *(const float4*)(xsrc + st * 32);
            const float4 v1 = *(const float4*)(xsrc + st * 32 + 4);
            g[0] = v0.x; g[1] = v0.y; g[2] = v0.z; g[3] = v0.w;
            g[4] = v1.x; g[5] = v1.y; g[6] = v1.z; g[7] = v1.w;
        } else {
#pragma unroll
            for (int j = 0; j < 8; ++j) g[j] = 0.f;
        }
        // 256 uint4 total (128 hi + 128 lo): tid<128 -> hi, else lo
        b_r = (tid < 128) ? b2h[st * 128 + tid] : b2l[st * 128 + (tid - 128)];
    };
    auto WRITE = [&]() {
        unsigned short h[8], l[8];
#pragma unroll
        for (int j = 0; j < 8; ++j) {
            const float v00 = __shfl(g[j], r00, 64);
            const float v01 = __shfl(g[j], r01, 64);
            const float v10 = __shfl(g[j], r10, 64);
            const float v11 = __shfl(g[j], r11, 64);
            const float v0 = v00 + fx * (v01 - v00);
            const float v1 = v10 + fx * (v11 - v10);
            const float a = v0 + fy * (v1 - v0);
            h[j] = f32_to_bf16_rne(a);
            l[j] = f32_to_bf16_rne(a - bf16_to_f32(h[j]));
        }
        *(uint4*)&AhS[lane >> 4][wid * 16 + (lane & 15)][0] =
            make_uint4(pck(h[0], h[1]), pck(h[2], h[3]), pck(h[4], h[5]), pck(h[6], h[7]));
        *(uint4*)&AlS[lane >> 4][wid * 16 + (lane & 15)][0] =
            make_uint4(pck(l[0], l[1]), pck(l[2], l[3]), pck(l[4], l[5]), pck(l[6], l[7]));
        if (tid < 128) ((uint4*)&BhS[0][0][0])[tid] = b_r;
        else           ((uint4*)&BlS[0][0][0])[tid - 128] = b_r;
    };

    LOAD(0);
    WRITE();
    __syncthreads();

    for (int st = 0; st < 24; ++st) {
        if (st < 23) LOAD(st + 1);
        const bf16x8 ah = *(const bf16x8*)&AhS[wid][lane][0];
        const bf16x8 al = *(const bf16x8*)&AlS[wid][lane][0];
#pragma unroll
        for (int q = 0; q < 2; ++q) {
            const bf16x8 bh = *(const bf16x8*)&BhS[q][lane][0];
            const bf16x8 blo = *(const bf16x8*)&BlS[q][lane][0];
            acc[q] = __builtin_amdgcn_mfma_f32_16x16x32_bf16(al, bh, acc[q], 0, 0, 0);
            acc[q] = __builtin_amdgcn_mfma_f32_16x16x32_bf16(ah, blo, acc[q], 0, 0, 0);
            acc[q] = __builtin_amdgcn_mfma_f32_16x16x32_bf16(ah, bh, acc[q], 0, 0, 0);
        }
        __syncthreads();
        if (st < 23) {
            WRITE();
            __syncthreads();
        }
    }

#pragma unroll
    for (int q = 0; q < 2; ++q)
#pragma unroll
        for (int r = 0; r < 4; ++r) {
            const int row = wid * 16 + (lane >> 4) * 4 + r;
            const int col = q * 16 + (lane & 15);
            out[((size_t)b * 64 + row) * 768 + n0 + col] = acc[q][r] + bias[col];
        }
}

// ---------------------------------------------------------------------------
// K4: image_part gather + 128->224 bilinear. Unchanged.
// ---------------------------------------------------------------------------
__global__ __launch_bounds__(256) void k_image(
    const float* __restrict__ img, const int* __restrict__ sel,
    float* __restrict__ out)
{
    const int idx = blockIdx.x * 256 + threadIdx.x;
    if (idx >= 16 * 3 * 224 * 224) return;
    const int ox = idx % 224;
    int t = idx / 224;
    const int oy = t % 224; t /= 224;
    const int c = t % 3;
    const int b = t / 3;
    const int s = sel[b];
    const int ry0 = (s / 9) * 48 - 32, cx0 = (s % 9) * 48 - 32;

    float sy = (oy + 0.5f) * (128.f / 224.f) - 0.5f;
    sy = fminf(fmaxf(sy, 0.f), 127.f);
    const int fy0 = (int)sy; const float wy = sy - (float)fy0;
    const int fy1 = (fy0 < 127) ? fy0 + 1 : 127;

    float sx = (ox + 0.5f) * (128.f / 224.f) - 0.5f;
    sx = fminf(fmaxf(sx, 0.f), 127.f);
    const int fx0 = (int)sx; const float wx = sx - (float)fx0;
    const int fx1 = (fx0 < 127) ? fx0 + 1 : 127;

    const float* ib = img + ((size_t)b * 3 + c) * 448 * 448;
    auto rd = [&](int py, int px) -> float {
        const int r = ry0 + py, cc = cx0 + px;
        return (r >= 0 && r < 448 && cc >= 0 && cc < 448) ? ib[r * 448 + cc] : 0.f;
    };
    const float g00 = rd(fy0, fx0), g01 = rd(fy0, fx1);
    const float g10 = rd(fy1, fx0), g11 = rd(fy1, fx1);
    const float v0 = g00 + wx * (g01 - g00);
    const float v1 = g10 + wx * (g11 - g10);
    out[idx] = v0 + wy * (v1 - v0);
}

// ---------------------------------------------------------------------------
extern "C" void kernel_launch(void* const* d_in, const int* in_sizes, int n_in,
                              void* d_out, int out_size, void* d_ws, size_t ws_size,
                              hipStream_t stream)
{
    const float* x    = (const float*)d_in[0];
    const float* mask = (const float*)d_in[1];
    const float* img  = (const float*)d_in[2];
    const float* Wfc  = (const float*)d_in[3];
    const float* bfc  = (const float*)d_in[4];
    const float* Wl   = (const float*)d_in[5];
    const float* bl   = (const float*)d_in[6];
    const float* Wm   = (const float*)d_in[7];
    const float* bm   = (const float*)d_in[8];
    const float* Ws   = (const float*)d_in[9];
    const float* bs   = (const float*)d_in[10];
    float* out = (float*)d_out;

    char* ws = (char*)d_ws;
    float* pmax          = (float*)ws;                       // 100352 B
    float* psum          = (float*)(ws + 102400);            // 100352 B
    int*   sel           = (int*)(ws + 204800);              // 64 B
    unsigned short* Bpkh = (unsigned short*)(ws + 262144);   // 393216 B
    unsigned short* Bpkl = (unsigned short*)(ws + 655360);   // 393216 B
    unsigned short* B2h  = (unsigned short*)(ws + 1048576);  // 1179648 B
    unsigned short* B2l  = (unsigned short*)(ws + 2228224);  // 1179648 B

    hipLaunchKernelGGL(k_prep,     dim3(768),    dim3(256), 0, stream,
                       Wfc, Wl, Wm, Ws, Bpkh, Bpkl, B2h, B2l);
    hipLaunchKernelGGL(k_logits_p, dim3(392, 2), dim3(256), 0, stream,
                       x, Bpkh, Bpkl, bfc, pmax, psum);
    hipLaunchKernelGGL(k_sel,      dim3(16),     dim3(128), 0, stream,
                       pmax, psum, mask, sel);
    hipLaunchKernelGGL(k_ff,       dim3(384),    dim3(256), 0, stream,
                       x, sel, B2h, B2l, bl, bm, bs, out);
    hipLaunchKernelGGL(k_image,    dim3(9408),   dim3(256), 0, stream,
                       img, sel, out + 786432);
}

// Round 9
// 201.189 us; speedup vs baseline: 1.3551x; 1.3551x over previous
//
#include <hip/hip_runtime.h>
#include <math.h>

typedef __attribute__((ext_vector_type(8))) short bf16x8;
typedef __attribute__((ext_vector_type(4))) float f32x4;

__device__ __forceinline__ unsigned short f32_to_bf16_rne(float f) {
    unsigned int u = __float_as_uint(f);
    unsigned int r = (u + 0x7FFFu + ((u >> 16) & 1u)) >> 16;
    return (unsigned short)r;
}
__device__ __forceinline__ float bf16_to_f32(unsigned short h) {
    return __uint_as_float(((unsigned int)h) << 16);
}
__device__ __forceinline__ unsigned int pck(unsigned short a, unsigned short b) {
    return (unsigned int)a | ((unsigned int)b << 16);
}

// ---------------------------------------------------------------------------
// K0: k_prep — split weights to bf16 hi/lo, pack into MFMA-frag-chunk layouts.
//  Wfc      -> Bpkh/Bpkl [24 steps][16 frags][64][8]      (classes padded 256)
//  Wl/Wm/Ws -> B2h/B2l   [24 tiles32][24 steps][2][64][8] (ff cols, 32/tile)
// granule: idx = k_oct*16 + (col&15), elem = k&7 (MFMA B lane map).
// ---------------------------------------------------------------------------
__global__ __launch_bounds__(256) void k_prep(
    const float* __restrict__ Wfc, const float* __restrict__ Wl,
    const float* __restrict__ Wm, const float* __restrict__ Ws,
    unsigned short* __restrict__ Bpkh, unsigned short* __restrict__ Bpkl,
    unsigned short* __restrict__ B2h, unsigned short* __restrict__ B2l)
{
    const int blk = blockIdx.x, tid = threadIdx.x;
    const float* src; int idx, rows, cbase; bool isfc;
    if (blk < 192)      { isfc = true;  idx = blk * 256 + tid;         src = Wfc; rows = 200; cbase = 0; }
    else if (blk < 336) { isfc = false; idx = (blk - 192) * 256 + tid; src = Wl;  rows = 192; cbase = 0; }
    else if (blk < 480) { isfc = false; idx = (blk - 336) * 256 + tid; src = Wm;  rows = 192; cbase = 192; }
    else                { isfc = false; idx = (blk - 480) * 256 + tid; src = Ws;  rows = 384; cbase = 384; }
    const int c = idx / 192;            // local row (class/col)
    const int kk = (idx % 192) * 4;     // k base (multiple of 4)
    unsigned short h0 = 0, h1 = 0, h2 = 0, h3 = 0, l0 = 0, l1 = 0, l2 = 0, l3 = 0;
    if (c < rows) {
        const float4 w = *(const float4*)&src[(size_t)c * 768 + kk];
        h0 = f32_to_bf16_rne(w.x); l0 = f32_to_bf16_rne(w.x - bf16_to_f32(h0));
        h1 = f32_to_bf16_rne(w.y); l1 = f32_to_bf16_rne(w.y - bf16_to_f32(h1));
        h2 = f32_to_bf16_rne(w.z); l2 = f32_to_bf16_rne(w.z - bf16_to_f32(h2));
        h3 = f32_to_bf16_rne(w.w); l3 = f32_to_bf16_rne(w.w - bf16_to_f32(h3));
    }
    const int step = kk >> 5, oct = (kk & 31) >> 3, elem = kk & 7;
    const uint2 uh = make_uint2(pck(h0, h1), pck(h2, h3));
    const uint2 ul = make_uint2(pck(l0, l1), pck(l2, l3));
    if (isfc) {
        const size_t off = (size_t)((step * 16 + (c >> 4)) * 64 + oct * 16 + (c & 15)) * 8 + elem;
        *(uint2*)&Bpkh[off] = uh;
        *(uint2*)&Bpkl[off] = ul;
    } else {
        const int cg = cbase + c;
        const int tt = cg >> 5, cc = cg & 31;
        const size_t off = (size_t)(((tt * 24 + step) * 2 + (cc >> 4)) * 64 + oct * 16 + (cc & 15)) * 8 + elem;
        *(uint2*)&B2h[off] = uh;
        *(uint2*)&B2l[off] = ul;
    }
}

// ---------------------------------------------------------------------------
// K1: logits GEMM + per-block softmax PARTIALS. BM=32, BN=128, BK=32.
// grid (392, 2) = 784 blocks; 4 waves, wave = 32 rows x 32 cols (2Mx2N frags).
// Single-buffer LDS (21.5 KB), issue-early/write-late, 2 barriers/step.
// ALL prefetch state in NAMED scalar registers (round-8 spill fix: capture
// arrays went to scratch -> 74 MB writes/dispatch).
// ---------------------------------------------------------------------------
__global__ __launch_bounds__(256) void k_logits_p(
    const float* __restrict__ x, const unsigned short* __restrict__ Bpkh,
    const unsigned short* __restrict__ Bpkl, const float* __restrict__ bfc,
    float* __restrict__ pmax, float* __restrict__ psum)
{
    __shared__ unsigned short Ah[2][64][8], Al[2][64][8];   // 4 KB
    __shared__ unsigned short Bh[8][64][8], Bl[8][64][8];   // 16 KB
    __shared__ float sbias[128];
    __shared__ float red[4][32], red2[4][32];

    const int tid = threadIdx.x;
    const int lane = tid & 63;
    const int wid = tid >> 6;                 // n-wave 0..3
    const int row0 = blockIdx.x * 32;
    const int cb = blockIdx.y;                // col-half

    if (tid < 128) {
        const int c = cb * 128 + tid;
        sbias[tid] = (c < 200) ? bfc[c] : -1e30f;
    }

    const int ar = tid & 31, kq = tid >> 5;   // A: row, k-quad(4 floats)
    const float* xb = x + (size_t)(row0 + ar) * 768 + kq * 4;
    const uint4* bhs = (const uint4*)Bpkh;
    const uint4* bls = (const uint4*)Bpkl;

    float4 agv;
    uint4 bgh0, bgh1, bgl0, bgl1;

    f32x4 acc[2][2];
    const f32x4 z = {0.f, 0.f, 0.f, 0.f};
#pragma unroll
    for (int mf = 0; mf < 2; ++mf)
#pragma unroll
        for (int q = 0; q < 2; ++q) acc[mf][q] = z;

    auto LOADAB = [&](int t) {
        agv = *(const float4*)(xb + t * 32);
        const int base = t * 1024 + cb * 512;
        bgh0 = bhs[base + tid];
        bgh1 = bhs[base + 256 + tid];
        bgl0 = bls[base + tid];
        bgl1 = bls[base + 256 + tid];
    };
    auto WRITEAB = [&]() {
        const unsigned short h0 = f32_to_bf16_rne(agv.x);
        const unsigned short l0 = f32_to_bf16_rne(agv.x - bf16_to_f32(h0));
        const unsigned short h1 = f32_to_bf16_rne(agv.y);
        const unsigned short l1 = f32_to_bf16_rne(agv.y - bf16_to_f32(h1));
        const unsigned short h2 = f32_to_bf16_rne(agv.z);
        const unsigned short l2 = f32_to_bf16_rne(agv.z - bf16_to_f32(h2));
        const unsigned short h3 = f32_to_bf16_rne(agv.w);
        const unsigned short l3 = f32_to_bf16_rne(agv.w - bf16_to_f32(h3));
        *(uint2*)&Ah[ar >> 4][(kq >> 1) * 16 + (ar & 15)][(kq & 1) * 4] =
            make_uint2(pck(h0, h1), pck(h2, h3));
        *(uint2*)&Al[ar >> 4][(kq >> 1) * 16 + (ar & 15)][(kq & 1) * 4] =
            make_uint2(pck(l0, l1), pck(l2, l3));
        uint4* bdh = (uint4*)&Bh[0][0][0];
        uint4* bdl = (uint4*)&Bl[0][0][0];
        bdh[tid] = bgh0;
        bdh[256 + tid] = bgh1;
        bdl[tid] = bgl0;
        bdl[256 + tid] = bgl1;
    };

    LOADAB(0);
    WRITEAB();
    __syncthreads();

    for (int t = 0; t < 24; ++t) {
        if (t < 23) LOADAB(t + 1);            // overlaps MFMA below
        bf16x8 ah[2], al2[2];
#pragma unroll
        for (int mf = 0; mf < 2; ++mf) {
            ah[mf]  = *(const bf16x8*)&Ah[mf][lane][0];
            al2[mf] = *(const bf16x8*)&Al[mf][lane][0];
        }
#pragma unroll
        for (int q = 0; q < 2; ++q) {
            const bf16x8 bh = *(const bf16x8*)&Bh[wid * 2 + q][lane][0];
            const bf16x8 bl = *(const bf16x8*)&Bl[wid * 2 + q][lane][0];
#pragma unroll
            for (int mf = 0; mf < 2; ++mf) {
                acc[mf][q] = __builtin_amdgcn_mfma_f32_16x16x32_bf16(al2[mf], bh, acc[mf][q], 0, 0, 0);
                acc[mf][q] = __builtin_amdgcn_mfma_f32_16x16x32_bf16(ah[mf], bl, acc[mf][q], 0, 0, 0);
                acc[mf][q] = __builtin_amdgcn_mfma_f32_16x16x32_bf16(ah[mf], bh, acc[mf][q], 0, 0, 0);
            }
        }
        __syncthreads();                      // all waves done reading LDS[t]
        if (t < 23) {
            WRITEAB();                        // vmcnt waits loads issued above
            __syncthreads();
        }
    }

    // ---- softmax partials over this block's 128 cols ----
    // acc[mf][q][r] = logit[row=mf*16+(lane>>4)*4+r][col=wid*32+q*16+(lane&15)]
    float bv[2];
#pragma unroll
    for (int q = 0; q < 2; ++q) bv[q] = sbias[wid * 32 + q * 16 + (lane & 15)];

#pragma unroll
    for (int mf = 0; mf < 2; ++mf)
#pragma unroll
        for (int r = 0; r < 4; ++r) {
            float mx = fmaxf(acc[mf][0][r] + bv[0], acc[mf][1][r] + bv[1]);
#pragma unroll
            for (int s = 1; s < 16; s <<= 1) mx = fmaxf(mx, __shfl_xor(mx, s, 64));
            if ((lane & 15) == 0) red[wid][mf * 16 + (lane >> 4) * 4 + r] = mx;
        }
    __syncthreads();
#pragma unroll
    for (int mf = 0; mf < 2; ++mf)
#pragma unroll
        for (int r = 0; r < 4; ++r) {
            const int row = mf * 16 + (lane >> 4) * 4 + r;
            const float m = fmaxf(fmaxf(red[0][row], red[1][row]),
                                  fmaxf(red[2][row], red[3][row]));
            float se = __expf(acc[mf][0][r] + bv[0] - m) + __expf(acc[mf][1][r] + bv[1] - m);
#pragma unroll
            for (int s = 1; s < 16; s <<= 1) se += __shfl_xor(se, s, 64);
            if ((lane & 15) == 0) red2[wid][row] = se;
        }
    __syncthreads();
    if (wid == 0 && (lane & 15) == 0) {
#pragma unroll
        for (int mf = 0; mf < 2; ++mf)
#pragma unroll
            for (int r = 0; r < 4; ++r) {
                const int row = mf * 16 + (lane >> 4) * 4 + r;
                const float m = fmaxf(fmaxf(red[0][row], red[1][row]),
                                      fmaxf(red[2][row], red[3][row]));
                pmax[(size_t)(row0 + row) * 2 + cb] = m;
                psum[(size_t)(row0 + row) * 2 + cb] =
                    red2[0][row] + red2[1][row] + red2[2][row] + red2[3][row];
            }
    }
}

// ---------------------------------------------------------------------------
// K2: combine softmax partials -> maxprob; pool 8x8/stride3/pad2; mask; argmax.
// ---------------------------------------------------------------------------
__global__ void k_sel(const float* __restrict__ pmax, const float* __restrict__ psum,
                      const float* __restrict__ mask, int* __restrict__ sel)
{
    __shared__ float mp[784];
    __shared__ float pl[81];
    const int b = blockIdx.x, tid = threadIdx.x;
    for (int i = tid; i < 784; i += blockDim.x) {
        const size_t row = (size_t)b * 784 + i;
        const float m0 = pmax[row * 2], m1 = pmax[row * 2 + 1];
        const float s0 = psum[row * 2], s1 = psum[row * 2 + 1];
        const float M = fmaxf(m0, m1);
        mp[i] = 1.0f / (s0 * __expf(m0 - M) + s1 * __expf(m1 - M));
    }
    __syncthreads();
    if (tid < 81) {
        const int pr = tid / 9, pc = tid % 9;
        float s = 0.f;
        for (int ki = 0; ki < 8; ++ki) {
            const int y = pr * 3 - 2 + ki;
            if (y < 0 || y >= 28) continue;
            for (int kj = 0; kj < 8; ++kj) {
                const int xx = pc * 3 - 2 + kj;
                if (xx < 0 || xx >= 28) continue;
                s += mp[y * 28 + xx];
            }
        }
        pl[tid] = mask[b * 81 + tid] * (s * (1.f / 64.f));
    }
    __syncthreads();
    if (tid == 0) {
        float best = pl[0]; int bi = 0;
        for (int i = 1; i < 81; ++i) if (pl[i] > best) { best = pl[i]; bi = i; }
        sel[b] = bi;
    }
}

__device__ __forceinline__ void rcoef8(int o, int n, int& f0, int& f1, float& w)
{
    float s = (o + 0.5f) * ((float)n * 0.125f) - 0.5f;
    s = fminf(fmaxf(s, 0.f), (float)(n - 1));
    f0 = (int)s;
    w = s - (float)f0;
    f1 = f0 + 1; if (f1 > n - 1) f1 = n - 1;
}

// ---------------------------------------------------------------------------
// K3: fused build + ff GEMM. BM=64(window rows), BN=32, grid = 16 b x 24 tiles
// = 384 blocks. 4 waves; wave = m-frag (16 rows) x 32 cols. LDS 12 KB,
// single-buffer, issue-early/write-late. Gather->NAMED float4 regs (spill fix),
// shfl bilinear per scalar.
// ---------------------------------------------------------------------------
__global__ __launch_bounds__(256) void k_ff(
    const float* __restrict__ x, const int* __restrict__ sel,
    const unsigned short* __restrict__ B2h, const unsigned short* __restrict__ B2l,
    const float* __restrict__ bl, const float* __restrict__ bm,
    const float* __restrict__ bs_, float* __restrict__ out)
{
    __shared__ unsigned short AhS[4][64][8], AlS[4][64][8];  // 8 KB
    __shared__ unsigned short BhS[2][64][8], BlS[2][64][8];  // 4 KB

    const int blk = blockIdx.x;
    const int b = blk / 24, t = blk % 24;
    const int n0 = t * 32;
    const int seg = (t < 6) ? 0 : ((t < 12) ? 1 : 2);
    const float* bias = (seg == 0) ? (bl + t * 32)
                      : (seg == 1) ? (bm + (t - 6) * 32)
                                   : (bs_ + (t - 12) * 32);
    const int s = sel[b];
    const int wy0 = (s / 9) * 3 - 2, wx0 = (s % 9) * 3 - 2;

    const int tid = threadIdx.x;
    const int lane = tid & 63;
    const int wid = tid >> 6;     // staging: k-octet; compute: m-frag

    // gather: lane = window position (8x8), wave = k-octet
    const int gy = wy0 + (lane >> 3), gx = wx0 + (lane & 7);
    const bool inb = (gy >= 0 && gy < 28 && gx >= 0 && gx < 28);
    const float* xsrc = x + ((size_t)b * 784 + (inb ? (gy * 28 + gx) : 0)) * 768 + wid * 8;

    // bilinear corners for output row = lane
    int r00, r01, r10, r11; float fx = 0.f, fy = 0.f;
    if (seg == 0) { r00 = r01 = r10 = r11 = lane; }
    else {
        const int nn = (seg == 1) ? 6 : 4, off = (seg == 1) ? 1 : 2;
        int f0y, f1y, f0x, f1x;
        rcoef8(lane >> 3, nn, f0y, f1y, fy);
        rcoef8(lane & 7, nn, f0x, f1x, fx);
        r00 = (off + f0y) * 8 + off + f0x;
        r01 = (off + f0y) * 8 + off + f1x;
        r10 = (off + f1y) * 8 + off + f0x;
        r11 = (off + f1y) * 8 + off + f1x;
    }

    // B: packed per (tile, step): 128 uint4 per half
    const uint4* b2h = (const uint4*)B2h + (size_t)t * 24 * 128;
    const uint4* b2l = (const uint4*)B2l + (size_t)t * 24 * 128;

    float4 g0v, g1v;
    uint4 b_r;

    f32x4 acc[2];
    const f32x4 z = {0.f, 0.f, 0.f, 0.f};
    acc[0] = z; acc[1] = z;

    auto LOAD = [&](int st) {
        if (inb) {
            g0v = *(const float4*)(xsrc + st * 32);
            g1v = *(const float4*)(xsrc + st * 32 + 4);
        } else {
            g0v = make_float4(0.f, 0.f, 0.f, 0.f);
            g1v = make_float4(0.f, 0.f, 0.f, 0.f);
        }
        // 256 uint4 total (128 hi + 128 lo): tid<128 -> hi, else lo
        b_r = (tid < 128) ? b2h[st * 128 + tid] : b2l[st * 128 + (tid - 128)];
    };
    auto bil = [&](float v) -> float {
        const float v00 = __shfl(v, r00, 64);
        const float v01 = __shfl(v, r01, 64);
        const float v10 = __shfl(v, r10, 64);
        const float v11 = __shfl(v, r11, 64);
        const float a0 = v00 + fx * (v01 - v00);
        const float a1 = v10 + fx * (v11 - v10);
        return a0 + fy * (a1 - a0);
    };
    auto WRITE = [&]() {
        const float a0 = bil(g0v.x), a1 = bil(g0v.y), a2 = bil(g0v.z), a3 = bil(g0v.w);
        const float a4 = bil(g1v.x), a5 = bil(g1v.y), a6 = bil(g1v.z), a7 = bil(g1v.w);
        const unsigned short h0 = f32_to_bf16_rne(a0);
        const unsigned short l0 = f32_to_bf16_rne(a0 - bf16_to_f32(h0));
        const unsigned short h1 = f32_to_bf16_rne(a1);
        const unsigned short l1 = f32_to_bf16_rne(a1 - bf16_to_f32(h1));
        const unsigned short h2 = f32_to_bf16_rne(a2);
        const unsigned short l2 = f32_to_bf16_rne(a2 - bf16_to_f32(h2));
        const unsigned short h3 = f32_to_bf16_rne(a3);
        const unsigned short l3 = f32_to_bf16_rne(a3 - bf16_to_f32(h3));
        const unsigned short h4 = f32_to_bf16_rne(a4);
        const unsigned short l4 = f32_to_bf16_rne(a4 - bf16_to_f32(h4));
        const unsigned short h5 = f32_to_bf16_rne(a5);
        const unsigned short l5 = f32_to_bf16_rne(a5 - bf16_to_f32(h5));
        const unsigned short h6 = f32_to_bf16_rne(a6);
        const unsigned short l6 = f32_to_bf16_rne(a6 - bf16_to_f32(h6));
        const unsigned short h7 = f32_to_bf16_rne(a7);
        const unsigned short l7 = f32_to_bf16_rne(a7 - bf16_to_f32(h7));
        *(uint4*)&AhS[lane >> 4][wid * 16 + (lane & 15)][0] =
            make_uint4(pck(h0, h1), pck(h2, h3), pck(h4, h5), pck(h6, h7));
        *(uint4*)&AlS[lane >> 4][wid * 16 + (lane & 15)][0] =
            make_uint4(pck(l0, l1), pck(l2, l3), pck(l4, l5), pck(l6, l7));
        if (tid < 128) ((uint4*)&BhS[0][0][0])[tid] = b_r;
        else           ((uint4*)&BlS[0][0][0])[tid - 128] = b_r;
    };

    LOAD(0);
    WRITE();
    __syncthreads();

    for (int st = 0; st < 24; ++st) {
        if (st < 23) LOAD(st + 1);
        const bf16x8 ah = *(const bf16x8*)&AhS[wid][lane][0];
        const bf16x8 al = *(const bf16x8*)&AlS[wid][lane][0];
#pragma unroll
        for (int q = 0; q < 2; ++q) {
            const bf16x8 bh = *(const bf16x8*)&BhS[q][lane][0];
            const bf16x8 blo = *(const bf16x8*)&BlS[q][lane][0];
            acc[q] = __builtin_amdgcn_mfma_f32_16x16x32_bf16(al, bh, acc[q], 0, 0, 0);
            acc[q] = __builtin_amdgcn_mfma_f32_16x16x32_bf16(ah, blo, acc[q], 0, 0, 0);
            acc[q] = __builtin_amdgcn_mfma_f32_16x16x32_bf16(ah, bh, acc[q], 0, 0, 0);
        }
        __syncthreads();
        if (st < 23) {
            WRITE();
            __syncthreads();
        }
    }

#pragma unroll
    for (int q = 0; q < 2; ++q)
#pragma unroll
        for (int r = 0; r < 4; ++r) {
            const int row = wid * 16 + (lane >> 4) * 4 + r;
            const int col = q * 16 + (lane & 15);
            out[((size_t)b * 64 + row) * 768 + n0 + col] = acc[q][r] + bias[col];
        }
}

// ---------------------------------------------------------------------------
// K4: image_part gather + 128->224 bilinear. Unchanged.
// ---------------------------------------------------------------------------
__global__ __launch_bounds__(256) void k_image(
    const float* __restrict__ img, const int* __restrict__ sel,
    float* __restrict__ out)
{
    const int idx = blockIdx.x * 256 + threadIdx.x;
    if (idx >= 16 * 3 * 224 * 224) return;
    const int ox = idx % 224;
    int t = idx / 224;
    const int oy = t % 224; t /= 224;
    const int c = t % 3;
    const int b = t / 3;
    const int s = sel[b];
    const int ry0 = (s / 9) * 48 - 32, cx0 = (s % 9) * 48 - 32;

    float sy = (oy + 0.5f) * (128.f / 224.f) - 0.5f;
    sy = fminf(fmaxf(sy, 0.f), 127.f);
    const int fy0 = (int)sy; const float wy = sy - (float)fy0;
    const int fy1 = (fy0 < 127) ? fy0 + 1 : 127;

    float sx = (ox + 0.5f) * (128.f / 224.f) - 0.5f;
    sx = fminf(fmaxf(sx, 0.f), 127.f);
    const int fx0 = (int)sx; const float wx = sx - (float)fx0;
    const int fx1 = (fx0 < 127) ? fx0 + 1 : 127;

    const float* ib = img + ((size_t)b * 3 + c) * 448 * 448;
    auto rd = [&](int py, int px) -> float {
        const int r = ry0 + py, cc = cx0 + px;
        return (r >= 0 && r < 448 && cc >= 0 && cc < 448) ? ib[r * 448 + cc] : 0.f;
    };
    const float g00 = rd(fy0, fx0), g01 = rd(fy0, fx1);
    const float g10 = rd(fy1, fx0), g11 = rd(fy1, fx1);
    const float v0 = g00 + wx * (g01 - g00);
    const float v1 = g10 + wx * (g11 - g10);
    out[idx] = v0 + wy * (v1 - v0);
}

// ---------------------------------------------------------------------------
extern "C" void kernel_launch(void* const* d_in, const int* in_sizes, int n_in,
                              void* d_out, int out_size, void* d_ws, size_t ws_size,
                              hipStream_t stream)
{
    const float* x    = (const float*)d_in[0];
    const float* mask = (const float*)d_in[1];
    const float* img  = (const float*)d_in[2];
    const float* Wfc  = (const float*)d_in[3];
    const float* bfc  = (const float*)d_in[4];
    const float* Wl   = (const float*)d_in[5];
    const float* bl   = (const float*)d_in[6];
    const float* Wm   = (const float*)d_in[7];
    const float* bm   = (const float*)d_in[8];
    const float* Ws   = (const float*)d_in[9];
    const float* bs   = (const float*)d_in[10];
    float* out = (float*)d_out;

    char* ws = (char*)d_ws;
    float* pmax          = (float*)ws;                       // 100352 B
    float* psum          = (float*)(ws + 102400);            // 100352 B
    int*   sel           = (int*)(ws + 204800);              // 64 B
    unsigned short* Bpkh = (unsigned short*)(ws + 262144);   // 393216 B
    unsigned short* Bpkl = (unsigned short*)(ws + 655360);   // 393216 B
    unsigned short* B2h  = (unsigned short*)(ws + 1048576);  // 1179648 B
    unsigned short* B2l  = (unsigned short*)(ws + 2228224);  // 1179648 B

    hipLaunchKernelGGL(k_prep,     dim3(768),    dim3(256), 0, stream,
                       Wfc, Wl, Wm, Ws, Bpkh, Bpkl, B2h, B2l);
    hipLaunchKernelGGL(k_logits_p, dim3(392, 2), dim3(256), 0, stream,
                       x, Bpkh, Bpkl, bfc, pmax, psum);
    hipLaunchKernelGGL(k_sel,      dim3(16),     dim3(128), 0, stream,
                       pmax, psum, mask, sel);
    hipLaunchKernelGGL(k_ff,       dim3(384),    dim3(256), 0, stream,
                       x, sel, B2h, B2l, bl, bm, bs, out);
    hipLaunchKernelGGL(k_image,    dim3(9408),   dim3(256), 0, stream,
                       img, sel, out + 786432);
}